// Round 3
// baseline (1532.566 us; speedup 1.0000x reference)
//
#include <hip/hip_runtime.h>
#include <math.h>

#define K_TOP 5
#define E_NUM 64
#define D_DIM 128
#define F_DIM 256
#define TM 64

typedef __attribute__((ext_vector_type(8))) short bf16x8;
typedef __attribute__((ext_vector_type(4))) float f32x4;

__device__ __forceinline__ short f2bf(float f) {
  union { float f; unsigned u; } v; v.f = f;
  unsigned r = v.u + 0x7fffu + ((v.u >> 16) & 1u);
  return (short)(r >> 16);
}

__device__ __forceinline__ float fast_tanh(float x) {
  float e = __expf(2.0f * x);
  return 1.0f - 2.0f / (e + 1.0f);
}

// ---------- setup kernels ----------
__global__ void k_wconv(const float* __restrict__ W, short* __restrict__ Wbf, int n) {
  int i = blockIdx.x * 256 + threadIdx.x;
  if (i < n) Wbf[i] = f2bf(W[i]);
}

__global__ void k_centers(const float* __restrict__ C, short* __restrict__ cnbf) {
  __shared__ float ws2[2];
  int e = blockIdx.x, t = threadIdx.x;
  float v = C[e * D_DIM + t];
  float s = v * v;
  s += __shfl_down(s, 32); s += __shfl_down(s, 16); s += __shfl_down(s, 8);
  s += __shfl_down(s, 4);  s += __shfl_down(s, 2);  s += __shfl_down(s, 1);
  if ((t & 63) == 0) ws2[t >> 6] = s;
  __syncthreads();
  float n = sqrtf(ws2[0] + ws2[1]);
  n = (n > 0.f) ? n : 1.f;
  cnbf[e * D_DIM + t] = f2bf(v / n);
}

__global__ void k_zero(float* __restrict__ p, int n) {
  int i = blockIdx.x * 256 + threadIdx.x;
  if (i < n) p[i] = 0.f;
}

// ---------- phase A: GEMM + tanh + sim + topk ----------
__launch_bounds__(256)
__global__ void k_phaseA(const float* __restrict__ x0, const float* __restrict__ x1,
                         const float* __restrict__ x2,
                         const short* __restrict__ Wbf, const float* __restrict__ bvec,
                         const short* __restrict__ cnbf,
                         float* __restrict__ out,
                         float* __restrict__ vals_ws, int* __restrict__ idx_ws,
                         float* __restrict__ dvis_ws, int N)
{
  // A bf16 [64][264] (33792B) aliased with xp f32 [64][132] (33792B); sim f32 [64][68]; rinv[64]
  __shared__ __align__(16) char smem[33792 + 17408 + 256];
  short (*A)[264]  = (short(*)[264])smem;
  float (*xp)[132] = (float(*)[132])smem;
  float (*sim)[68] = (float(*)[68])(smem + 33792);
  float* rinv      = (float*)(smem + 33792 + 17408);

  const int t = threadIdx.x;
  const int s = blockIdx.y;
  const float* x = (s == 0) ? x0 : ((s == 1) ? x1 : x2);
  const int r0 = blockIdx.x * TM;
  const int m = min(TM, N - r0);
  float* out_s = out + (size_t)s * N * D_DIM;

  // stage x tile -> bf16 LDS (zero-pad rows >= m)
  #pragma unroll
  for (int i = 0; i < 16; ++i) {
    int f4 = t + i * 256;                 // 0..4095 float4 index
    int row = f4 >> 6, c4 = f4 & 63;
    float4 v = make_float4(0.f, 0.f, 0.f, 0.f);
    if (row < m) v = *(const float4*)(x + (size_t)(r0 + row) * F_DIM + (c4 << 2));
    short4 sv; sv.x = f2bf(v.x); sv.y = f2bf(v.y); sv.z = f2bf(v.z); sv.w = f2bf(v.w);
    *(short4*)&A[row][c4 << 2] = sv;
  }
  __syncthreads();

  const int w = t >> 6, l = t & 63;
  const int lrow = l & 15;
  const int lk8  = (l >> 4) << 3;
  const int colbase = w << 5;             // waves split the 128 output cols

  f32x4 acc[4][2];
  #pragma unroll
  for (int a_ = 0; a_ < 4; ++a_)
    #pragma unroll
    for (int b_ = 0; b_ < 2; ++b_)
      #pragma unroll
      for (int q = 0; q < 4; ++q) acc[a_][b_][q] = 0.f;

  #pragma unroll
  for (int kk = 0; kk < 8; ++kk) {
    const int k = (kk << 5) + lk8;
    bf16x8 af[4], bfr[2];
    #pragma unroll
    for (int rt = 0; rt < 4; ++rt)
      af[rt] = *(const bf16x8*)&A[(rt << 4) + lrow][k];
    #pragma unroll
    for (int ct = 0; ct < 2; ++ct)
      bfr[ct] = *(const bf16x8*)(Wbf + (size_t)(colbase + (ct << 4) + lrow) * F_DIM + k);
    #pragma unroll
    for (int rt = 0; rt < 4; ++rt)
      #pragma unroll
      for (int ct = 0; ct < 2; ++ct)
        acc[rt][ct] = __builtin_amdgcn_mfma_f32_16x16x32_bf16(af[rt], bfr[ct], acc[rt][ct], 0, 0, 0);
  }
  __syncthreads();   // all A reads done before overwriting with xp

  // tanh(acc + b) -> xp LDS
  #pragma unroll
  for (int ct = 0; ct < 2; ++ct) {
    const int col = colbase + (ct << 4) + lrow;
    const float bb = bvec[col];
    #pragma unroll
    for (int rt = 0; rt < 4; ++rt)
      #pragma unroll
      for (int q = 0; q < 4; ++q) {
        int row = (rt << 4) + ((l >> 4) << 2) + q;  // C layout: col=l&15, row=(l>>4)*4+reg
        xp[row][col] = fast_tanh(acc[rt][ct][q] + bb);
      }
  }
  __syncthreads();

  // xp -> global (coalesced float4)
  #pragma unroll
  for (int i = 0; i < 8; ++i) {
    int f4 = t + i * 256;
    int row = f4 >> 5, c4 = f4 & 31;
    if (row < m) {
      float4 v;
      v.x = xp[row][(c4 << 2)];     v.y = xp[row][(c4 << 2) + 1];
      v.z = xp[row][(c4 << 2) + 2]; v.w = xp[row][(c4 << 2) + 3];
      *(float4*)(out_s + (size_t)(r0 + row) * D_DIM + (c4 << 2)) = v;
    }
  }
  // row norms (4 threads/row)
  {
    int row = t >> 2, q = t & 3;
    float ss = 0.f;
    #pragma unroll
    for (int j = 0; j < 32; ++j) { float v = xp[row][(q << 5) + j]; ss += v * v; }
    ss += __shfl_xor(ss, 1);
    ss += __shfl_xor(ss, 2);
    if (q == 0) { float nn = sqrtf(ss); rinv[row] = 1.f / ((nn > 0.f) ? nn : 1.f); }
  }
  __syncthreads();

  // sim = xp @ cn^T (raw dot; scale by rinv at topk)
  const int ebase = w << 4;               // waves split the 64 edges
  f32x4 acc2[4];
  #pragma unroll
  for (int rt = 0; rt < 4; ++rt)
    #pragma unroll
    for (int q = 0; q < 4; ++q) acc2[rt][q] = 0.f;

  #pragma unroll
  for (int kk = 0; kk < 4; ++kk) {
    const int k = (kk << 5) + lk8;
    bf16x8 bc = *(const bf16x8*)(cnbf + (size_t)(ebase + lrow) * D_DIM + k);
    #pragma unroll
    for (int rt = 0; rt < 4; ++rt) {
      const float* src = &xp[(rt << 4) + lrow][k];
      float4 a0 = *(const float4*)(src);
      float4 a1 = *(const float4*)(src + 4);
      bf16x8 af;
      af[0] = f2bf(a0.x); af[1] = f2bf(a0.y); af[2] = f2bf(a0.z); af[3] = f2bf(a0.w);
      af[4] = f2bf(a1.x); af[5] = f2bf(a1.y); af[6] = f2bf(a1.z); af[7] = f2bf(a1.w);
      acc2[rt] = __builtin_amdgcn_mfma_f32_16x16x32_bf16(af, bc, acc2[rt], 0, 0, 0);
    }
  }
  #pragma unroll
  for (int rt = 0; rt < 4; ++rt)
    #pragma unroll
    for (int q = 0; q < 4; ++q)
      sim[(rt << 4) + ((l >> 4) << 2) + q][ebase + lrow] = acc2[rt][q];
  __syncthreads();

  // topk per row (strict > keeps lower index on ties, matching jax top_k)
  if (t < m) {
    const int row = t;
    const float rv = rinv[row];
    float v0 = -2.f, v1 = -2.f, v2 = -2.f, v3 = -2.f, v4 = -2.f;
    int i0 = 0, i1 = 0, i2 = 0, i3 = 0, i4 = 0;
    for (int e = 0; e < E_NUM; ++e) {
      float v = sim[row][e] * rv;
      v = fminf(fmaxf(v, -1.f), 1.f);
      if (v > v4) {
        if (v > v0)      { v4=v3;i4=i3; v3=v2;i3=i2; v2=v1;i2=i1; v1=v0;i1=i0; v0=v; i0=e; }
        else if (v > v1) { v4=v3;i4=i3; v3=v2;i3=i2; v2=v1;i2=i1; v1=v; i1=e; }
        else if (v > v2) { v4=v3;i4=i3; v3=v2;i3=i2; v2=v; i2=e; }
        else if (v > v3) { v4=v3;i4=i3; v3=v; i3=e; }
        else             { v4=v; i4=e; }
      }
    }
    float Dv = v0 + v1 + v2 + v3 + v4;
    float dvq = 1.f / (sqrtf(Dv) + 1e-6f);
    size_t gr = (size_t)s * N + (r0 + row);
    dvis_ws[gr] = dvq;
    float* vp = vals_ws + gr * 5;
    int*   ip = idx_ws  + gr * 5;
    vp[0]=v0; vp[1]=v1; vp[2]=v2; vp[3]=v3; vp[4]=v4;
    ip[0]=i0; ip[1]=i1; ip[2]=i2; ip[3]=i3; ip[4]=i4;
  }
}

// ---------- phase A2: scatter-accumulate D_e and step2 ----------
__launch_bounds__(256)
__global__ void k_scatter(const float* __restrict__ out,
                          const float* __restrict__ vals_ws, const int* __restrict__ idx_ws,
                          const float* __restrict__ dvis_ws,
                          float* __restrict__ De_g, float* __restrict__ step2_g,
                          int N, int P)
{
  __shared__ float s2[E_NUM][D_DIM];
  __shared__ float de[E_NUM];
  const int t = threadIdx.x;
  const int s = blockIdx.y;
  const int part = blockIdx.x;
  for (int i = t; i < E_NUM * D_DIM; i += 256) ((float*)s2)[i] = 0.f;
  if (t < E_NUM) de[t] = 0.f;
  __syncthreads();

  const int chunk = (N + P - 1) / P;
  const int rbeg = part * chunk;
  const int rend = min(N, rbeg + chunk);
  const int d = t & 127, half = t >> 7;
  const float* xps = out + (size_t)s * N * D_DIM;

  for (int r = rbeg + half; r < rend; r += 2) {
    size_t gr = (size_t)s * N + r;
    float dv = dvis_ws[gr];
    float st1 = xps[(size_t)r * D_DIM + d] * dv;
    const float* vp = vals_ws + gr * 5;
    const int*   ip = idx_ws  + gr * 5;
    #pragma unroll
    for (int k = 0; k < K_TOP; ++k) {
      float val = vp[k]; int e = ip[k];
      atomicAdd(&s2[e][d], val * st1);
      if (d == 0) atomicAdd(&de[e], val);
    }
  }
  __syncthreads();
  float* s2g = step2_g + (size_t)s * E_NUM * D_DIM;
  for (int i = t; i < E_NUM * D_DIM; i += 256) atomicAdd(&s2g[i], ((float*)s2)[i]);
  if (t < E_NUM) atomicAdd(&De_g[s * E_NUM + t], de[t]);
}

// ---------- step3 = step2 * de_inv ----------
__global__ void k_step3(const float* __restrict__ step2_g, const float* __restrict__ De_g,
                        float* __restrict__ step3_g) {
  int i = blockIdx.x * 256 + threadIdx.x;
  if (i < 3 * E_NUM * D_DIM) {
    int s = i / (E_NUM * D_DIM);
    int e = (i / D_DIM) % E_NUM;
    step3_g[i] = step2_g[i] / (De_g[s * E_NUM + e] + 1e-6f);
  }
}

// ---------- phase B: combine + fused pairwise distance ----------
__launch_bounds__(256)
__global__ void k_combine(float* __restrict__ out, const float* __restrict__ vals_ws,
                          const int* __restrict__ idx_ws, const float* __restrict__ dvis_ws,
                          const float* __restrict__ step3_g, const float* __restrict__ alpha_p,
                          int N)
{
  const float alpha = *alpha_p;
  const float ca = 2.0f - alpha;
  const int t = threadIdx.x;
  const int lane = t & 31;
  const int rg = t >> 5;                  // 8 rows per block pass
  const int d0 = lane << 2;
  const int ngroups = (N + 7) / 8;
  for (int g = blockIdx.x; g < ngroups; g += (int)gridDim.x) {
    int r = g * 8 + rg;
    if (r >= N) continue;
    float fa0=0,fa1=0,fa2=0,fa3=0;
    float sp = 0.f, sn = 0.f;
    #pragma unroll
    for (int s = 0; s < 3; ++s) {
      size_t gr = (size_t)s * N + r;
      float dv = dvis_ws[gr];
      const float* vp = vals_ws + gr * 5;
      const int*   ip = idx_ws  + gr * 5;
      float* op = out + gr * D_DIM + d0;
      float4 xv = *(const float4*)op;
      float h0=0,h1=0,h2=0,h3=0;
      const float* s3 = step3_g + (size_t)s * E_NUM * D_DIM;
      #pragma unroll
      for (int k = 0; k < K_TOP; ++k) {
        float val = vp[k]; int e = ip[k];
        float4 sr = *(const float4*)(s3 + (size_t)e * D_DIM + d0);
        h0 += val * sr.x; h1 += val * sr.y; h2 += val * sr.z; h3 += val * sr.w;
      }
      float adv = alpha * dv;
      float f0 = ca * xv.x + adv * h0;
      float f1 = ca * xv.y + adv * h1;
      float f2 = ca * xv.z + adv * h2;
      float f3 = ca * xv.w + adv * h3;
      *(float4*)op = make_float4(f0, f1, f2, f3);
      if (s == 0) { fa0=f0; fa1=f1; fa2=f2; fa3=f3; }
      else if (s == 1) {
        float d_;
        d_ = fa0-f0+1e-6f; sp += d_*d_;  d_ = fa1-f1+1e-6f; sp += d_*d_;
        d_ = fa2-f2+1e-6f; sp += d_*d_;  d_ = fa3-f3+1e-6f; sp += d_*d_;
      } else {
        float d_;
        d_ = fa0-f0+1e-6f; sn += d_*d_;  d_ = fa1-f1+1e-6f; sn += d_*d_;
        d_ = fa2-f2+1e-6f; sn += d_*d_;  d_ = fa3-f3+1e-6f; sn += d_*d_;
      }
    }
    sp += __shfl_xor(sp, 1); sp += __shfl_xor(sp, 2); sp += __shfl_xor(sp, 4);
    sp += __shfl_xor(sp, 8); sp += __shfl_xor(sp, 16);
    sn += __shfl_xor(sn, 1); sn += __shfl_xor(sn, 2); sn += __shfl_xor(sn, 4);
    sn += __shfl_xor(sn, 8); sn += __shfl_xor(sn, 16);
    if (lane == 0) out[(size_t)3 * N * D_DIM + r] = sqrtf(sn) - sqrtf(sp);
  }
}

extern "C" void kernel_launch(void* const* d_in, const int* in_sizes, int n_in,
                              void* d_out, int out_size, void* d_ws, size_t ws_size,
                              hipStream_t stream) {
  const float* xa      = (const float*)d_in[0];
  const float* xpos    = (const float*)d_in[1];
  const float* xn      = (const float*)d_in[2];
  const float* W       = (const float*)d_in[3];
  const float* bvec    = (const float*)d_in[4];
  const float* centers = (const float*)d_in[5];
  const float* alpha   = (const float*)d_in[6];
  float* out = (float*)d_out;
  const int N = in_sizes[0] / F_DIM;

  char* ws = (char*)d_ws;
  short* Wbf   = (short*)(ws);              // 65536 B
  short* cnbf  = (short*)(ws + 65536);      // 16384 B
  float* De_g  = (float*)(ws + 81920);      // 768 B   (zeroed together with step2)
  float* step2 = (float*)(ws + 82688);      // 98304 B
  float* step3 = (float*)(ws + 180992);     // 98304 B
  size_t o = 279296;
  float* vals = (float*)(ws + o); o += (size_t)3 * N * 5 * 4;
  int*   idxs = (int*)(ws + o);   o += (size_t)3 * N * 5 * 4;
  float* dvis = (float*)(ws + o);

  k_wconv<<<(D_DIM * F_DIM + 255) / 256, 256, 0, stream>>>(W, Wbf, D_DIM * F_DIM);
  k_centers<<<E_NUM, D_DIM, 0, stream>>>(centers, cnbf);
  k_zero<<<(24768 + 255) / 256, 256, 0, stream>>>(De_g, 24768);

  dim3 gA((N + TM - 1) / TM, 3);
  k_phaseA<<<gA, 256, 0, stream>>>(xa, xpos, xn, Wbf, bvec, cnbf, out, vals, idxs, dvis, N);

  const int P = 340;
  k_scatter<<<dim3(P, 3), 256, 0, stream>>>(out, vals, idxs, dvis, De_g, step2, N, P);
  k_step3<<<(3 * E_NUM * D_DIM + 255) / 256, 256, 0, stream>>>(step2, De_g, step3);
  k_combine<<<2048, 256, 0, stream>>>(out, vals, idxs, dvis, step3, alpha, N);
}

// Round 4
// 812.553 us; speedup vs baseline: 1.8861x; 1.8861x over previous
//
#include <hip/hip_runtime.h>
#include <math.h>

#define K_TOP 5
#define E_NUM 64
#define D_DIM 128
#define F_DIM 256
#define TM 64
#define SC_WAVES 2

typedef __attribute__((ext_vector_type(8))) short bf16x8;
typedef __attribute__((ext_vector_type(4))) float f32x4;

__device__ __forceinline__ short f2bf(float f) {
  union { float f; unsigned u; } v; v.f = f;
  unsigned r = v.u + 0x7fffu + ((v.u >> 16) & 1u);
  return (short)(r >> 16);
}

__device__ __forceinline__ float fast_tanh(float x) {
  float e = __expf(2.0f * x);
  return 1.0f - 2.0f / (e + 1.0f);
}

// ---------- setup kernels ----------
__global__ void k_wconv(const float* __restrict__ W, short* __restrict__ Wbf, int n) {
  int i = blockIdx.x * 256 + threadIdx.x;
  if (i < n) Wbf[i] = f2bf(W[i]);
}

__global__ void k_centers(const float* __restrict__ C, short* __restrict__ cnbf) {
  __shared__ float ws2[2];
  int e = blockIdx.x, t = threadIdx.x;
  float v = C[e * D_DIM + t];
  float s = v * v;
  s += __shfl_down(s, 32); s += __shfl_down(s, 16); s += __shfl_down(s, 8);
  s += __shfl_down(s, 4);  s += __shfl_down(s, 2);  s += __shfl_down(s, 1);
  if ((t & 63) == 0) ws2[t >> 6] = s;
  __syncthreads();
  float n = sqrtf(ws2[0] + ws2[1]);
  n = (n > 0.f) ? n : 1.f;
  cnbf[e * D_DIM + t] = f2bf(v / n);
}

__global__ void k_zero(float* __restrict__ p, int n) {
  int i = blockIdx.x * 256 + threadIdx.x;
  if (i < n) p[i] = 0.f;
}

// ---------- phase A: GEMM + tanh + sim + topk ----------
__launch_bounds__(256)
__global__ void k_phaseA(const float* __restrict__ x0, const float* __restrict__ x1,
                         const float* __restrict__ x2,
                         const short* __restrict__ Wbf, const float* __restrict__ bvec,
                         const short* __restrict__ cnbf,
                         float* __restrict__ out,
                         float* __restrict__ vals_ws, int* __restrict__ idx_ws,
                         float* __restrict__ dvis_ws, int N)
{
  // A bf16 [64][264] (33792B) aliased with xp f32 [64][132] (33792B); sim f32 [64][68]; rinv[64]
  __shared__ __align__(16) char smem[33792 + 17408 + 256];
  short (*A)[264]  = (short(*)[264])smem;
  float (*xp)[132] = (float(*)[132])smem;
  float (*sim)[68] = (float(*)[68])(smem + 33792);
  float* rinv      = (float*)(smem + 33792 + 17408);

  const int t = threadIdx.x;
  const int s = blockIdx.y;
  const float* x = (s == 0) ? x0 : ((s == 1) ? x1 : x2);
  const int r0 = blockIdx.x * TM;
  const int m = min(TM, N - r0);
  float* out_s = out + (size_t)s * N * D_DIM;

  // stage x tile -> bf16 LDS (zero-pad rows >= m)
  #pragma unroll
  for (int i = 0; i < 16; ++i) {
    int f4 = t + i * 256;                 // 0..4095 float4 index
    int row = f4 >> 6, c4 = f4 & 63;
    float4 v = make_float4(0.f, 0.f, 0.f, 0.f);
    if (row < m) v = *(const float4*)(x + (size_t)(r0 + row) * F_DIM + (c4 << 2));
    short4 sv; sv.x = f2bf(v.x); sv.y = f2bf(v.y); sv.z = f2bf(v.z); sv.w = f2bf(v.w);
    *(short4*)&A[row][c4 << 2] = sv;
  }
  __syncthreads();

  const int w = t >> 6, l = t & 63;
  const int lrow = l & 15;
  const int lk8  = (l >> 4) << 3;
  const int colbase = w << 5;             // waves split the 128 output cols

  f32x4 acc[4][2];
  #pragma unroll
  for (int a_ = 0; a_ < 4; ++a_)
    #pragma unroll
    for (int b_ = 0; b_ < 2; ++b_)
      #pragma unroll
      for (int q = 0; q < 4; ++q) acc[a_][b_][q] = 0.f;

  #pragma unroll
  for (int kk = 0; kk < 8; ++kk) {
    const int k = (kk << 5) + lk8;
    bf16x8 af[4], bfr[2];
    #pragma unroll
    for (int rt = 0; rt < 4; ++rt)
      af[rt] = *(const bf16x8*)&A[(rt << 4) + lrow][k];
    #pragma unroll
    for (int ct = 0; ct < 2; ++ct)
      bfr[ct] = *(const bf16x8*)(Wbf + (size_t)(colbase + (ct << 4) + lrow) * F_DIM + k);
    #pragma unroll
    for (int rt = 0; rt < 4; ++rt)
      #pragma unroll
      for (int ct = 0; ct < 2; ++ct)
        acc[rt][ct] = __builtin_amdgcn_mfma_f32_16x16x32_bf16(af[rt], bfr[ct], acc[rt][ct], 0, 0, 0);
  }
  __syncthreads();   // all A reads done before overwriting with xp

  // tanh(acc + b) -> xp LDS
  #pragma unroll
  for (int ct = 0; ct < 2; ++ct) {
    const int col = colbase + (ct << 4) + lrow;
    const float bb = bvec[col];
    #pragma unroll
    for (int rt = 0; rt < 4; ++rt)
      #pragma unroll
      for (int q = 0; q < 4; ++q) {
        int row = (rt << 4) + ((l >> 4) << 2) + q;  // C layout: col=l&15, row=(l>>4)*4+reg
        xp[row][col] = fast_tanh(acc[rt][ct][q] + bb);
      }
  }
  __syncthreads();

  // xp -> global (coalesced float4)
  #pragma unroll
  for (int i = 0; i < 8; ++i) {
    int f4 = t + i * 256;
    int row = f4 >> 5, c4 = f4 & 31;
    if (row < m) {
      float4 v;
      v.x = xp[row][(c4 << 2)];     v.y = xp[row][(c4 << 2) + 1];
      v.z = xp[row][(c4 << 2) + 2]; v.w = xp[row][(c4 << 2) + 3];
      *(float4*)(out_s + (size_t)(r0 + row) * D_DIM + (c4 << 2)) = v;
    }
  }
  // row norms (4 threads/row)
  {
    int row = t >> 2, q = t & 3;
    float ss = 0.f;
    #pragma unroll
    for (int j = 0; j < 32; ++j) { float v = xp[row][(q << 5) + j]; ss += v * v; }
    ss += __shfl_xor(ss, 1);
    ss += __shfl_xor(ss, 2);
    if (q == 0) { float nn = sqrtf(ss); rinv[row] = 1.f / ((nn > 0.f) ? nn : 1.f); }
  }
  __syncthreads();

  // sim = xp @ cn^T (raw dot; scale by rinv at topk)
  const int ebase = w << 4;               // waves split the 64 edges
  f32x4 acc2[4];
  #pragma unroll
  for (int rt = 0; rt < 4; ++rt)
    #pragma unroll
    for (int q = 0; q < 4; ++q) acc2[rt][q] = 0.f;

  #pragma unroll
  for (int kk = 0; kk < 4; ++kk) {
    const int k = (kk << 5) + lk8;
    bf16x8 bc = *(const bf16x8*)(cnbf + (size_t)(ebase + lrow) * D_DIM + k);
    #pragma unroll
    for (int rt = 0; rt < 4; ++rt) {
      const float* src = &xp[(rt << 4) + lrow][k];
      float4 a0 = *(const float4*)(src);
      float4 a1 = *(const float4*)(src + 4);
      bf16x8 af;
      af[0] = f2bf(a0.x); af[1] = f2bf(a0.y); af[2] = f2bf(a0.z); af[3] = f2bf(a0.w);
      af[4] = f2bf(a1.x); af[5] = f2bf(a1.y); af[6] = f2bf(a1.z); af[7] = f2bf(a1.w);
      acc2[rt] = __builtin_amdgcn_mfma_f32_16x16x32_bf16(af, bc, acc2[rt], 0, 0, 0);
    }
  }
  #pragma unroll
  for (int rt = 0; rt < 4; ++rt)
    #pragma unroll
    for (int q = 0; q < 4; ++q)
      sim[(rt << 4) + ((l >> 4) << 2) + q][ebase + lrow] = acc2[rt][q];
  __syncthreads();

  // topk per row (strict > keeps lower index on ties, matching jax top_k)
  if (t < m) {
    const int row = t;
    const float rv = rinv[row];
    float v0 = -2.f, v1 = -2.f, v2 = -2.f, v3 = -2.f, v4 = -2.f;
    int i0 = 0, i1 = 0, i2 = 0, i3 = 0, i4 = 0;
    for (int e = 0; e < E_NUM; ++e) {
      float v = sim[row][e] * rv;
      v = fminf(fmaxf(v, -1.f), 1.f);
      if (v > v4) {
        if (v > v0)      { v4=v3;i4=i3; v3=v2;i3=i2; v2=v1;i2=i1; v1=v0;i1=i0; v0=v; i0=e; }
        else if (v > v1) { v4=v3;i4=i3; v3=v2;i3=i2; v2=v1;i2=i1; v1=v; i1=e; }
        else if (v > v2) { v4=v3;i4=i3; v3=v2;i3=i2; v2=v; i2=e; }
        else if (v > v3) { v4=v3;i4=i3; v3=v; i3=e; }
        else             { v4=v; i4=e; }
      }
    }
    float Dv = v0 + v1 + v2 + v3 + v4;
    float dvq = 1.f / (sqrtf(Dv) + 1e-6f);
    size_t gr = (size_t)s * N + (r0 + row);
    dvis_ws[gr] = dvq;
    float* vp = vals_ws + gr * 5;
    int*   ip = idx_ws  + gr * 5;
    vp[0]=v0; vp[1]=v1; vp[2]=v2; vp[3]=v3; vp[4]=v4;
    ip[0]=i0; ip[1]=i1; ip[2]=i2; ip[3]=i3; ip[4]=i4;
  }
}

// ---------- phase A2: scatter-accumulate D_e and step2 (private per-wave LDS, no atomics) ----------
// grid (P, 3 streams, 2 d-halves), 128 threads = 2 waves; each wave owns a private [64e][64d] copy.
__launch_bounds__(128)
__global__ void k_scatter(const float* __restrict__ out,
                          const float* __restrict__ vals_ws, const int* __restrict__ idx_ws,
                          const float* __restrict__ dvis_ws,
                          float* __restrict__ De_g, float* __restrict__ step2_g,
                          int N, int P)
{
  __shared__ float s2[SC_WAVES][E_NUM][64];   // 32768 B
  __shared__ float de[SC_WAVES][E_NUM];       // 512 B
  const int t = threadIdx.x;
  const int wid = t >> 6, l = t & 63;
  const int s = blockIdx.y;
  const int half = blockIdx.z;
  const int d0 = half << 6;

  for (int i = t; i < SC_WAVES * E_NUM * 64; i += 128) ((float*)s2)[i] = 0.f;
  for (int i = t; i < SC_WAVES * E_NUM; i += 128) ((float*)de)[i] = 0.f;
  __syncthreads();

  const int chunk = (N + P - 1) / P;
  const int rbeg = blockIdx.x * chunk;
  const int rend = min(N, rbeg + chunk);
  const float* xps = out + (size_t)s * N * D_DIM + d0;
  float (*m2)[64] = s2[wid];
  float* mde = de[wid];

#define LOADROW(rr, X, DV, V0, V1, V2, V3, V4, E0, E1, E2, E3, E4) { \
    size_t gr_ = (size_t)s * N + (rr); \
    X = xps[(size_t)(rr) * D_DIM + l]; \
    DV = dvis_ws[gr_]; \
    const float* vp_ = vals_ws + gr_ * 5; \
    const int*   ip_ = idx_ws  + gr_ * 5; \
    V0 = vp_[0]; V1 = vp_[1]; V2 = vp_[2]; V3 = vp_[3]; V4 = vp_[4]; \
    E0 = ip_[0]; E1 = ip_[1]; E2 = ip_[2]; E3 = ip_[3]; E4 = ip_[4]; }

  int r = rbeg + wid;
  float xv = 0.f, dv = 0.f, va0 = 0.f, va1 = 0.f, va2 = 0.f, va3 = 0.f, va4 = 0.f;
  int ea0 = 0, ea1 = 0, ea2 = 0, ea3 = 0, ea4 = 0;
  if (r < rend) LOADROW(r, xv, dv, va0, va1, va2, va3, va4, ea0, ea1, ea2, ea3, ea4);
  while (r < rend) {
    const int rn = r + SC_WAVES;
    float xn = 0.f, dn = 0.f, w0 = 0.f, w1 = 0.f, w2 = 0.f, w3 = 0.f, w4 = 0.f;
    int f0 = 0, f1 = 0, f2 = 0, f3 = 0, f4 = 0;
    if (rn < rend) LOADROW(rn, xn, dn, w0, w1, w2, w3, w4, f0, f1, f2, f3, f4);
    const float st1 = xv * dv;
    m2[ea0][l] += va0 * st1;
    m2[ea1][l] += va1 * st1;
    m2[ea2][l] += va2 * st1;
    m2[ea3][l] += va3 * st1;
    m2[ea4][l] += va4 * st1;
    if (half == 0 && l == 0) {
      mde[ea0] += va0; mde[ea1] += va1; mde[ea2] += va2; mde[ea3] += va3; mde[ea4] += va4;
    }
    xv = xn; dv = dn;
    va0 = w0; va1 = w1; va2 = w2; va3 = w3; va4 = w4;
    ea0 = f0; ea1 = f1; ea2 = f2; ea3 = f3; ea4 = f4;
    r = rn;
  }
#undef LOADROW

  __syncthreads();
  // flush: sum the per-wave copies, one global atomic per element
  for (int i = t; i < E_NUM * 64; i += 128) {
    int e = i >> 6, dd = i & 63;
    float v = s2[0][e][dd] + s2[1][e][dd];
    atomicAdd(&step2_g[((size_t)s * E_NUM + e) * D_DIM + d0 + dd], v);
  }
  if (half == 0) {
    for (int i = t; i < E_NUM; i += 128)
      atomicAdd(&De_g[s * E_NUM + i], de[0][i] + de[1][i]);
  }
}

// ---------- step3 = step2 * de_inv ----------
__global__ void k_step3(const float* __restrict__ step2_g, const float* __restrict__ De_g,
                        float* __restrict__ step3_g) {
  int i = blockIdx.x * 256 + threadIdx.x;
  if (i < 3 * E_NUM * D_DIM) {
    int s = i / (E_NUM * D_DIM);
    int e = (i / D_DIM) % E_NUM;
    step3_g[i] = step2_g[i] / (De_g[s * E_NUM + e] + 1e-6f);
  }
}

// ---------- phase B: combine + fused pairwise distance ----------
__launch_bounds__(256)
__global__ void k_combine(float* __restrict__ out, const float* __restrict__ vals_ws,
                          const int* __restrict__ idx_ws, const float* __restrict__ dvis_ws,
                          const float* __restrict__ step3_g, const float* __restrict__ alpha_p,
                          int N)
{
  const float alpha = *alpha_p;
  const float ca = 2.0f - alpha;
  const int t = threadIdx.x;
  const int lane = t & 31;
  const int rg = t >> 5;                  // 8 rows per block pass
  const int d0 = lane << 2;
  const int ngroups = (N + 7) / 8;
  for (int g = blockIdx.x; g < ngroups; g += (int)gridDim.x) {
    int r = g * 8 + rg;
    if (r >= N) continue;
    float fa0=0,fa1=0,fa2=0,fa3=0;
    float sp = 0.f, sn = 0.f;
    #pragma unroll
    for (int s = 0; s < 3; ++s) {
      size_t gr = (size_t)s * N + r;
      float dv = dvis_ws[gr];
      const float* vp = vals_ws + gr * 5;
      const int*   ip = idx_ws  + gr * 5;
      float* op = out + gr * D_DIM + d0;
      float4 xv = *(const float4*)op;
      float h0=0,h1=0,h2=0,h3=0;
      const float* s3 = step3_g + (size_t)s * E_NUM * D_DIM;
      #pragma unroll
      for (int k = 0; k < K_TOP; ++k) {
        float val = vp[k]; int e = ip[k];
        float4 sr = *(const float4*)(s3 + (size_t)e * D_DIM + d0);
        h0 += val * sr.x; h1 += val * sr.y; h2 += val * sr.z; h3 += val * sr.w;
      }
      float adv = alpha * dv;
      float f0 = ca * xv.x + adv * h0;
      float f1 = ca * xv.y + adv * h1;
      float f2 = ca * xv.z + adv * h2;
      float f3 = ca * xv.w + adv * h3;
      *(float4*)op = make_float4(f0, f1, f2, f3);
      if (s == 0) { fa0=f0; fa1=f1; fa2=f2; fa3=f3; }
      else if (s == 1) {
        float d_;
        d_ = fa0-f0+1e-6f; sp += d_*d_;  d_ = fa1-f1+1e-6f; sp += d_*d_;
        d_ = fa2-f2+1e-6f; sp += d_*d_;  d_ = fa3-f3+1e-6f; sp += d_*d_;
      } else {
        float d_;
        d_ = fa0-f0+1e-6f; sn += d_*d_;  d_ = fa1-f1+1e-6f; sn += d_*d_;
        d_ = fa2-f2+1e-6f; sn += d_*d_;  d_ = fa3-f3+1e-6f; sn += d_*d_;
      }
    }
    sp += __shfl_xor(sp, 1); sp += __shfl_xor(sp, 2); sp += __shfl_xor(sp, 4);
    sp += __shfl_xor(sp, 8); sp += __shfl_xor(sp, 16);
    sn += __shfl_xor(sn, 1); sn += __shfl_xor(sn, 2); sn += __shfl_xor(sn, 4);
    sn += __shfl_xor(sn, 8); sn += __shfl_xor(sn, 16);
    if (lane == 0) out[(size_t)3 * N * D_DIM + r] = sqrtf(sn) - sqrtf(sp);
  }
}

extern "C" void kernel_launch(void* const* d_in, const int* in_sizes, int n_in,
                              void* d_out, int out_size, void* d_ws, size_t ws_size,
                              hipStream_t stream) {
  const float* xa      = (const float*)d_in[0];
  const float* xpos    = (const float*)d_in[1];
  const float* xn      = (const float*)d_in[2];
  const float* W       = (const float*)d_in[3];
  const float* bvec    = (const float*)d_in[4];
  const float* centers = (const float*)d_in[5];
  const float* alpha   = (const float*)d_in[6];
  float* out = (float*)d_out;
  const int N = in_sizes[0] / F_DIM;

  char* ws = (char*)d_ws;
  short* Wbf   = (short*)(ws);              // 65536 B
  short* cnbf  = (short*)(ws + 65536);      // 16384 B
  float* De_g  = (float*)(ws + 81920);      // 768 B   (zeroed together with step2)
  float* step2 = (float*)(ws + 82688);      // 98304 B
  float* step3 = (float*)(ws + 180992);     // 98304 B
  size_t o = 279296;
  float* vals = (float*)(ws + o); o += (size_t)3 * N * 5 * 4;
  int*   idxs = (int*)(ws + o);   o += (size_t)3 * N * 5 * 4;
  float* dvis = (float*)(ws + o);

  k_wconv<<<(D_DIM * F_DIM + 255) / 256, 256, 0, stream>>>(W, Wbf, D_DIM * F_DIM);
  k_centers<<<E_NUM, D_DIM, 0, stream>>>(centers, cnbf);
  k_zero<<<(24768 + 255) / 256, 256, 0, stream>>>(De_g, 24768);

  dim3 gA((N + TM - 1) / TM, 3);
  k_phaseA<<<gA, 256, 0, stream>>>(xa, xpos, xn, Wbf, bvec, cnbf, out, vals, idxs, dvis, N);

  const int P = 170;   // 170*3*2 = 1020 blocks, ~4 blocks/CU at 33KB LDS
  k_scatter<<<dim3(P, 3, 2), 128, 0, stream>>>(out, vals, idxs, dvis, De_g, step2, N, P);
  k_step3<<<(3 * E_NUM * D_DIM + 255) / 256, 256, 0, stream>>>(step2, De_g, step3);
  k_combine<<<2048, 256, 0, stream>>>(out, vals, idxs, dvis, step3, alpha, N);
}

// Round 6
// 746.004 us; speedup vs baseline: 2.0544x; 1.0892x over previous
//
#include <hip/hip_runtime.h>
#include <math.h>

#define K_TOP 5
#define E_NUM 64
#define D_DIM 128
#define F_DIM 256
#define TM 64
#define SC_WAVES 2

typedef __attribute__((ext_vector_type(8))) short bf16x8;
typedef __attribute__((ext_vector_type(4))) float f32x4;

__device__ __forceinline__ short f2bf(float f) {
  union { float f; unsigned u; } v; v.f = f;
  unsigned r = v.u + 0x7fffu + ((v.u >> 16) & 1u);
  return (short)(r >> 16);
}

__device__ __forceinline__ float bf2f(short h) {
  union { unsigned u; float f; } v; v.u = ((unsigned)(unsigned short)h) << 16;
  return v.f;
}

__device__ __forceinline__ float fast_tanh(float x) {
  float e = __expf(2.0f * x);
  return 1.0f - 2.0f / (e + 1.0f);
}

// ---------- setup kernels ----------
__global__ void k_wconv(const float* __restrict__ W, short* __restrict__ Wbf, int n) {
  int i = blockIdx.x * 256 + threadIdx.x;
  if (i < n) Wbf[i] = f2bf(W[i]);
}

__global__ void k_centers(const float* __restrict__ C, short* __restrict__ cnbf) {
  __shared__ float ws2[2];
  int e = blockIdx.x, t = threadIdx.x;
  float v = C[e * D_DIM + t];
  float s = v * v;
  s += __shfl_down(s, 32); s += __shfl_down(s, 16); s += __shfl_down(s, 8);
  s += __shfl_down(s, 4);  s += __shfl_down(s, 2);  s += __shfl_down(s, 1);
  if ((t & 63) == 0) ws2[t >> 6] = s;
  __syncthreads();
  float n = sqrtf(ws2[0] + ws2[1]);
  n = (n > 0.f) ? n : 1.f;
  cnbf[e * D_DIM + t] = f2bf(v / n);
}

__global__ void k_zero(float* __restrict__ p, int n) {
  int i = blockIdx.x * 256 + threadIdx.x;
  if (i < n) p[i] = 0.f;
}

// ---------- phase A: GEMM + tanh + sim(swapped) + in-register topk ----------
__launch_bounds__(256, 4)
__global__ void k_phaseA(const float* __restrict__ x0, const float* __restrict__ x1,
                         const float* __restrict__ x2,
                         const short* __restrict__ Wbf, const float* __restrict__ bvec,
                         const short* __restrict__ cnbf,
                         float* __restrict__ out,
                         float* __restrict__ vals_ws, int* __restrict__ idx_ws,
                         float* __restrict__ dvis_ws, int N)
{
  // A bf16 [64][264] (33792B) aliased with xpb bf16 [64][136] (17408B)
  __shared__ __align__(16) char smem[33792];
  short (*A)[264]   = (short(*)[264])smem;
  short (*xpb)[136] = (short(*)[136])smem;

  const int t = threadIdx.x;
  const int s = blockIdx.y;
  const float* x = (s == 0) ? x0 : ((s == 1) ? x1 : x2);
  const int r0 = blockIdx.x * TM;
  const int m = min(TM, N - r0);
  float* out_s = out + (size_t)s * N * D_DIM;

  // stage x tile -> bf16 LDS (zero-pad rows >= m); cvt_pk packs 2 f32->2 bf16/inst
  #pragma unroll
  for (int i = 0; i < 16; ++i) {
    int f4 = t + i * 256;                 // 0..4095 float4 index
    int row = f4 >> 6, c4 = f4 & 63;
    float4 v = make_float4(0.f, 0.f, 0.f, 0.f);
    if (row < m) v = *(const float4*)(x + (size_t)(r0 + row) * F_DIM + (c4 << 2));
    unsigned p01, p23;
    asm("v_cvt_pk_bf16_f32 %0, %1, %2" : "=v"(p01) : "v"(v.x), "v"(v.y));
    asm("v_cvt_pk_bf16_f32 %0, %1, %2" : "=v"(p23) : "v"(v.z), "v"(v.w));
    *(uint2*)&A[row][c4 << 2] = make_uint2(p01, p23);
  }
  __syncthreads();

  const int w = t >> 6, l = t & 63;
  const int lrow = l & 15;
  const int lk8  = (l >> 4) << 3;
  const int g4   = (l >> 4) << 2;
  const int colbase = w << 5;             // waves split the 128 output cols

  f32x4 acc[4][2];
  #pragma unroll
  for (int a_ = 0; a_ < 4; ++a_)
    #pragma unroll
    for (int b_ = 0; b_ < 2; ++b_)
      #pragma unroll
      for (int q = 0; q < 4; ++q) acc[a_][b_][q] = 0.f;

  #pragma unroll
  for (int kk = 0; kk < 8; ++kk) {
    const int k = (kk << 5) + lk8;
    bf16x8 af[4], bfr[2];
    #pragma unroll
    for (int rt = 0; rt < 4; ++rt)
      af[rt] = *(const bf16x8*)&A[(rt << 4) + lrow][k];
    #pragma unroll
    for (int ct = 0; ct < 2; ++ct)
      bfr[ct] = *(const bf16x8*)(Wbf + (size_t)(colbase + (ct << 4) + lrow) * F_DIM + k);
    #pragma unroll
    for (int rt = 0; rt < 4; ++rt)
      #pragma unroll
      for (int ct = 0; ct < 2; ++ct)
        acc[rt][ct] = __builtin_amdgcn_mfma_f32_16x16x32_bf16(af[rt], bfr[ct], acc[rt][ct], 0, 0, 0);
  }
  __syncthreads();   // all A reads done before overwriting with xpb

  // tanh(acc + b): f32 -> global directly; bf16 -> LDS xpb
  #pragma unroll
  for (int ct = 0; ct < 2; ++ct) {
    const int col = colbase + (ct << 4) + lrow;
    const float bb = bvec[col];
    #pragma unroll
    for (int rt = 0; rt < 4; ++rt)
      #pragma unroll
      for (int q = 0; q < 4; ++q) {
        int row = (rt << 4) + g4 + q;     // C layout: col=l&15, row=(l>>4)*4+reg
        float v = fast_tanh(acc[rt][ct][q] + bb);
        if (row < m) out_s[(size_t)(r0 + row) * D_DIM + col] = v;
        xpb[row][col] = f2bf(v);
      }
  }
  __syncthreads();

  // sim^T = centers @ xp^T : wave w owns xp-rows [16w,16w+16); lane l -> row 16w+(l&15)
  // D[col = lane&15 = xp-row][rowreg = edge]; lane accumulates 16 edges: et*16 + g4 + q
  const int rowbase = w << 4;
  f32x4 acc2[4];
  #pragma unroll
  for (int et = 0; et < 4; ++et)
    #pragma unroll
    for (int q = 0; q < 4; ++q) acc2[et][q] = 0.f;

  float ss = 0.f;
  #pragma unroll
  for (int kt = 0; kt < 4; ++kt) {
    const int k = (kt << 5) + lk8;
    bf16x8 bx = *(const bf16x8*)&xpb[rowbase + lrow][k];
    #pragma unroll
    for (int j = 0; j < 8; ++j) { float f = bf2f(bx[j]); ss += f * f; }
    #pragma unroll
    for (int et = 0; et < 4; ++et) {
      bf16x8 bc = *(const bf16x8*)(cnbf + (size_t)((et << 4) + lrow) * D_DIM + k);
      acc2[et] = __builtin_amdgcn_mfma_f32_16x16x32_bf16(bc, bx, acc2[et], 0, 0, 0);
    }
  }
  // full row norm: lanes {r, r+16, r+32, r+48} hold disjoint k-partitions
  ss += __shfl_xor(ss, 16);
  ss += __shfl_xor(ss, 32);
  float nn = sqrtf(ss);
  const float rv = 1.f / ((nn > 0.f) ? nn : 1.f);

  // in-register topk: local top5 of this lane's 16 edges (ascending e => strict >)
  float bv0 = -2.f, bv1 = -2.f, bv2 = -2.f, bv3 = -2.f, bv4 = -2.f;
  int   bi0 = 64,   bi1 = 64,   bi2 = 64,   bi3 = 64,   bi4 = 64;
  #pragma unroll
  for (int et = 0; et < 4; ++et)
    #pragma unroll
    for (int q = 0; q < 4; ++q) {
      float v = acc2[et][q] * rv;
      v = fminf(fmaxf(v, -1.f), 1.f);
      int e = (et << 4) + g4 + q;
      bool c0 = v > bv0, c1 = v > bv1, c2 = v > bv2, c3 = v > bv3, c4 = v > bv4;
      bv4 = c4 ? (c3 ? bv3 : v) : bv4;  bi4 = c4 ? (c3 ? bi3 : e) : bi4;
      bv3 = c3 ? (c2 ? bv2 : v) : bv3;  bi3 = c3 ? (c2 ? bi2 : e) : bi3;
      bv2 = c2 ? (c1 ? bv1 : v) : bv2;  bi2 = c2 ? (c1 ? bi1 : e) : bi2;
      bv1 = c1 ? (c0 ? bv0 : v) : bv1;  bi1 = c1 ? (c0 ? bi0 : e) : bi1;
      bv0 = c0 ? v : bv0;               bi0 = c0 ? e : bi0;
    }

  // merge across the 4 lanes sharing a row (xor 16, then xor 32); tie -> lower idx first
  #pragma unroll
  for (int mm = 16; mm <= 32; mm <<= 1) {
    float ov0 = __shfl_xor(bv0, mm), ov1 = __shfl_xor(bv1, mm), ov2 = __shfl_xor(bv2, mm),
          ov3 = __shfl_xor(bv3, mm), ov4 = __shfl_xor(bv4, mm);
    int   oi0 = __shfl_xor(bi0, mm), oi1 = __shfl_xor(bi1, mm), oi2 = __shfl_xor(bi2, mm),
          oi3 = __shfl_xor(bi3, mm), oi4 = __shfl_xor(bi4, mm);
    #define INS2(vv, ii) { \
      bool c0 = (vv > bv0) || (vv == bv0 && ii < bi0); \
      bool c1 = (vv > bv1) || (vv == bv1 && ii < bi1); \
      bool c2 = (vv > bv2) || (vv == bv2 && ii < bi2); \
      bool c3 = (vv > bv3) || (vv == bv3 && ii < bi3); \
      bool c4 = (vv > bv4) || (vv == bv4 && ii < bi4); \
      bv4 = c4 ? (c3 ? bv3 : vv) : bv4;  bi4 = c4 ? (c3 ? bi3 : ii) : bi4; \
      bv3 = c3 ? (c2 ? bv2 : vv) : bv3;  bi3 = c3 ? (c2 ? bi2 : ii) : bi3; \
      bv2 = c2 ? (c1 ? bv1 : vv) : bv2;  bi2 = c2 ? (c1 ? bi1 : ii) : bi2; \
      bv1 = c1 ? (c0 ? bv0 : vv) : bv1;  bi1 = c1 ? (c0 ? bi0 : ii) : bi1; \
      bv0 = c0 ? vv : bv0;               bi0 = c0 ? ii : bi0; }
    INS2(ov0, oi0); INS2(ov1, oi1); INS2(ov2, oi2); INS2(ov3, oi3); INS2(ov4, oi4);
    #undef INS2
  }

  if (l < 16) {
    int row = rowbase + l;
    if (row < m) {
      float Dv = bv0 + bv1 + bv2 + bv3 + bv4;
      float dvq = 1.f / (sqrtf(Dv) + 1e-6f);
      size_t gr = (size_t)s * N + (r0 + row);
      dvis_ws[gr] = dvq;
      float* vp = vals_ws + gr * 5;
      int*   ip = idx_ws  + gr * 5;
      vp[0] = bv0; vp[1] = bv1; vp[2] = bv2; vp[3] = bv3; vp[4] = bv4;
      ip[0] = bi0; ip[1] = bi1; ip[2] = bi2; ip[3] = bi3; ip[4] = bi4;
    }
  }
}

// ---------- phase A2: scatter-accumulate D_e and step2 (private per-wave LDS, no atomics) ----------
__launch_bounds__(128)
__global__ void k_scatter(const float* __restrict__ out,
                          const float* __restrict__ vals_ws, const int* __restrict__ idx_ws,
                          const float* __restrict__ dvis_ws,
                          float* __restrict__ De_g, float* __restrict__ step2_g,
                          int N, int P)
{
  __shared__ float s2[SC_WAVES][E_NUM][64];   // 32768 B
  __shared__ float de[SC_WAVES][E_NUM];       // 512 B
  const int t = threadIdx.x;
  const int wid = t >> 6, l = t & 63;
  const int s = blockIdx.y;
  const int half = blockIdx.z;
  const int d0 = half << 6;

  for (int i = t; i < SC_WAVES * E_NUM * 64; i += 128) ((float*)s2)[i] = 0.f;
  for (int i = t; i < SC_WAVES * E_NUM; i += 128) ((float*)de)[i] = 0.f;
  __syncthreads();

  const int chunk = (N + P - 1) / P;
  const int rbeg = blockIdx.x * chunk;
  const int rend = min(N, rbeg + chunk);
  const float* xps = out + (size_t)s * N * D_DIM + d0;
  float (*m2)[64] = s2[wid];
  float* mde = de[wid];

#define LOADROW(rr, X, DV, V0, V1, V2, V3, V4, E0, E1, E2, E3, E4) { \
    size_t gr_ = (size_t)s * N + (rr); \
    X = xps[(size_t)(rr) * D_DIM + l]; \
    DV = dvis_ws[gr_]; \
    const float* vp_ = vals_ws + gr_ * 5; \
    const int*   ip_ = idx_ws  + gr_ * 5; \
    V0 = vp_[0]; V1 = vp_[1]; V2 = vp_[2]; V3 = vp_[3]; V4 = vp_[4]; \
    E0 = ip_[0]; E1 = ip_[1]; E2 = ip_[2]; E3 = ip_[3]; E4 = ip_[4]; }

  int r = rbeg + wid;
  float xv = 0.f, dv = 0.f, va0 = 0.f, va1 = 0.f, va2 = 0.f, va3 = 0.f, va4 = 0.f;
  int ea0 = 0, ea1 = 0, ea2 = 0, ea3 = 0, ea4 = 0;
  if (r < rend) LOADROW(r, xv, dv, va0, va1, va2, va3, va4, ea0, ea1, ea2, ea3, ea4);
  while (r < rend) {
    const int rn = r + SC_WAVES;
    float xn = 0.f, dn = 0.f, w0 = 0.f, w1 = 0.f, w2 = 0.f, w3 = 0.f, w4 = 0.f;
    int f0 = 0, f1 = 0, f2 = 0, f3 = 0, f4 = 0;
    if (rn < rend) LOADROW(rn, xn, dn, w0, w1, w2, w3, w4, f0, f1, f2, f3, f4);
    const float st1 = xv * dv;
    m2[ea0][l] += va0 * st1;
    m2[ea1][l] += va1 * st1;
    m2[ea2][l] += va2 * st1;
    m2[ea3][l] += va3 * st1;
    m2[ea4][l] += va4 * st1;
    if (half == 0 && l == 0) {
      mde[ea0] += va0; mde[ea1] += va1; mde[ea2] += va2; mde[ea3] += va3; mde[ea4] += va4;
    }
    xv = xn; dv = dn;
    va0 = w0; va1 = w1; va2 = w2; va3 = w3; va4 = w4;
    ea0 = f0; ea1 = f1; ea2 = f2; ea3 = f3; ea4 = f4;
    r = rn;
  }
#undef LOADROW

  __syncthreads();
  for (int i = t; i < E_NUM * 64; i += 128) {
    int e = i >> 6, dd = i & 63;
    float v = s2[0][e][dd] + s2[1][e][dd];
    atomicAdd(&step2_g[((size_t)s * E_NUM + e) * D_DIM + d0 + dd], v);
  }
  if (half == 0) {
    for (int i = t; i < E_NUM; i += 128)
      atomicAdd(&De_g[s * E_NUM + i], de[0][i] + de[1][i]);
  }
}

// ---------- step3 = step2 * de_inv ----------
__global__ void k_step3(const float* __restrict__ step2_g, const float* __restrict__ De_g,
                        float* __restrict__ step3_g) {
  int i = blockIdx.x * 256 + threadIdx.x;
  if (i < 3 * E_NUM * D_DIM) {
    int s = i / (E_NUM * D_DIM);
    int e = (i / D_DIM) % E_NUM;
    step3_g[i] = step2_g[i] / (De_g[s * E_NUM + e] + 1e-6f);
  }
}

// ---------- phase B: combine + fused pairwise distance ----------
__launch_bounds__(256)
__global__ void k_combine(float* __restrict__ out, const float* __restrict__ vals_ws,
                          const int* __restrict__ idx_ws, const float* __restrict__ dvis_ws,
                          const float* __restrict__ step3_g, const float* __restrict__ alpha_p,
                          int N)
{
  const float alpha = *alpha_p;
  const float ca = 2.0f - alpha;
  const int t = threadIdx.x;
  const int lane = t & 31;
  const int rg = t >> 5;                  // 8 rows per block pass
  const int d0 = lane << 2;
  const int ngroups = (N + 7) / 8;
  for (int g = blockIdx.x; g < ngroups; g += (int)gridDim.x) {
    int r = g * 8 + rg;
    if (r >= N) continue;
    float fa0=0,fa1=0,fa2=0,fa3=0;
    float sp = 0.f, sn = 0.f;
    #pragma unroll
    for (int s = 0; s < 3; ++s) {
      size_t gr = (size_t)s * N + r;
      float dv = dvis_ws[gr];
      const float* vp = vals_ws + gr * 5;
      const int*   ip = idx_ws  + gr * 5;
      float* op = out + gr * D_DIM + d0;
      float4 xv = *(const float4*)op;
      float h0=0,h1=0,h2=0,h3=0;
      const float* s3 = step3_g + (size_t)s * E_NUM * D_DIM;
      #pragma unroll
      for (int k = 0; k < K_TOP; ++k) {
        float val = vp[k]; int e = ip[k];
        float4 sr = *(const float4*)(s3 + (size_t)e * D_DIM + d0);
        h0 += val * sr.x; h1 += val * sr.y; h2 += val * sr.z; h3 += val * sr.w;
      }
      float adv = alpha * dv;
      float f0 = ca * xv.x + adv * h0;
      float f1 = ca * xv.y + adv * h1;
      float f2 = ca * xv.z + adv * h2;
      float f3 = ca * xv.w + adv * h3;
      *(float4*)op = make_float4(f0, f1, f2, f3);
      if (s == 0) { fa0=f0; fa1=f1; fa2=f2; fa3=f3; }
      else if (s == 1) {
        float d_;
        d_ = fa0-f0+1e-6f; sp += d_*d_;  d_ = fa1-f1+1e-6f; sp += d_*d_;
        d_ = fa2-f2+1e-6f; sp += d_*d_;  d_ = fa3-f3+1e-6f; sp += d_*d_;
      } else {
        float d_;
        d_ = fa0-f0+1e-6f; sn += d_*d_;  d_ = fa1-f1+1e-6f; sn += d_*d_;
        d_ = fa2-f2+1e-6f; sn += d_*d_;  d_ = fa3-f3+1e-6f; sn += d_*d_;
      }
    }
    sp += __shfl_xor(sp, 1); sp += __shfl_xor(sp, 2); sp += __shfl_xor(sp, 4);
    sp += __shfl_xor(sp, 8); sp += __shfl_xor(sp, 16);
    sn += __shfl_xor(sn, 1); sn += __shfl_xor(sn, 2); sn += __shfl_xor(sn, 4);
    sn += __shfl_xor(sn, 8); sn += __shfl_xor(sn, 16);
    if (lane == 0) out[(size_t)3 * N * D_DIM + r] = sqrtf(sn) - sqrtf(sp);
  }
}

extern "C" void kernel_launch(void* const* d_in, const int* in_sizes, int n_in,
                              void* d_out, int out_size, void* d_ws, size_t ws_size,
                              hipStream_t stream) {
  const float* xa      = (const float*)d_in[0];
  const float* xpos    = (const float*)d_in[1];
  const float* xn      = (const float*)d_in[2];
  const float* W       = (const float*)d_in[3];
  const float* bvec    = (const float*)d_in[4];
  const float* centers = (const float*)d_in[5];
  const float* alpha   = (const float*)d_in[6];
  float* out = (float*)d_out;
  const int N = in_sizes[0] / F_DIM;

  char* ws = (char*)d_ws;
  short* Wbf   = (short*)(ws);              // 65536 B
  short* cnbf  = (short*)(ws + 65536);      // 16384 B
  float* De_g  = (float*)(ws + 81920);      // 768 B   (zeroed together with step2)
  float* step2 = (float*)(ws + 82688);      // 98304 B
  float* step3 = (float*)(ws + 180992);     // 98304 B
  size_t o = 279296;
  float* vals = (float*)(ws + o); o += (size_t)3 * N * 5 * 4;
  int*   idxs = (int*)(ws + o);   o += (size_t)3 * N * 5 * 4;
  float* dvis = (float*)(ws + o);

  k_wconv<<<(D_DIM * F_DIM + 255) / 256, 256, 0, stream>>>(W, Wbf, D_DIM * F_DIM);
  k_centers<<<E_NUM, D_DIM, 0, stream>>>(centers, cnbf);
  k_zero<<<(24768 + 255) / 256, 256, 0, stream>>>(De_g, 24768);

  dim3 gA((N + TM - 1) / TM, 3);
  k_phaseA<<<gA, 256, 0, stream>>>(xa, xpos, xn, Wbf, bvec, cnbf, out, vals, idxs, dvis, N);

  const int P = 170;   // 170*3*2 = 1020 blocks
  k_scatter<<<dim3(P, 3, 2), 128, 0, stream>>>(out, vals, idxs, dvis, De_g, step2, N, P);
  k_step3<<<(3 * E_NUM * D_DIM + 255) / 256, 256, 0, stream>>>(step2, De_g, step3);
  k_combine<<<2048, 256, 0, stream>>>(out, vals, idxs, dvis, step3, alpha, N);
}